// Round 1
// 200.597 us; speedup vs baseline: 1.0115x; 1.0115x over previous
//
#include <hip/hip_runtime.h>
#include <hip/hip_bf16.h>
#include <stdint.h>

#define BDIM 2048
#define HDIM 1024
#define XDIM 1024
#define BH (BDIM*HDIM)
#define WSEG 1048576  // 1M elements per segment

typedef __attribute__((ext_vector_type(8))) short short8;
typedef __attribute__((ext_vector_type(4))) float float4v;

__device__ __forceinline__ void gload16(const void* g, void* l) {
    __builtin_amdgcn_global_load_lds(
        (const __attribute__((address_space(1))) unsigned int*)g,
        (__attribute__((address_space(3))) unsigned int*)l, 16, 0, 0);
}

__device__ __forceinline__ unsigned pack2(float a, float b) {
    __hip_bfloat162 v = __float22bfloat162_rn(make_float2(a, b));
    return *reinterpret_cast<unsigned*>(&v);
}
__device__ __forceinline__ uint2 pack4(float4 f) {
    return make_uint2(pack2(f.x, f.y), pack2(f.z, f.w));
}
__device__ __forceinline__ float2 up2(unsigned u) {
    __hip_bfloat162 v = *reinterpret_cast<__hip_bfloat162*>(&u);
    return __bfloat1622float2(v);
}

// ---------------- prep_all: fp32 -> bf16 for everything the GEMM eats ----------------
// ws bf16 segment map (1M elems each):
//   segs 0..7  : wxi,wxf,wxc,wxo,whi,whf,whc,who
//   segs 8..9  : x (rows 0..1023, 1024..2047)
//   segs 10..17: hm[g][rowhalf] = h0 * maskHg   (hm_g contiguous as 2048x1024)
__global__ __launch_bounds__(256) void prep_all_k(
    const float* __restrict__ w0, const float* __restrict__ w1,
    const float* __restrict__ w2, const float* __restrict__ w3,
    const float* __restrict__ w4, const float* __restrict__ w5,
    const float* __restrict__ w6, const float* __restrict__ w7,
    const float* __restrict__ x, const float* __restrict__ h0,
    const float* __restrict__ mI, const float* __restrict__ mF,
    const float* __restrict__ mC, const float* __restrict__ mO,
    uint2* __restrict__ dst) {
    const int seg = blockIdx.y;
    const int i = blockIdx.x * 256 + threadIdx.x;   // float4 index within segment (262144)
    float4 f;
    if (seg < 10) {
        const float* base;
        switch (seg) {
            case 0: base = w0; break; case 1: base = w1; break;
            case 2: base = w2; break; case 3: base = w3; break;
            case 4: base = w4; break; case 5: base = w5; break;
            case 6: base = w6; break; case 7: base = w7; break;
            default: base = x + (size_t)(seg - 8) * WSEG; break;
        }
        f = ((const float4*)base)[i];
    } else {
        const int s = seg - 10;
        const int g = s >> 1, half = s & 1;
        const float* mp = (g == 0) ? mI : (g == 1) ? mF : (g == 2) ? mC : mO;
        float4 h = ((const float4*)(h0 + (size_t)half * WSEG))[i];
        float4 m = ((const float4*)(mp + (size_t)half * WSEG))[i];
        f = make_float4(h.x * m.x, h.y * m.y, h.z * m.z, h.w * m.w);
    }
    dst[(size_t)seg * (WSEG / 4) + i] = pack4(f);
}

// ---------------- gemm split-K, 256x256 tile, 8-phase pipelined schedule ----------------
// part[z=2g+half][b][n] = A_half[b,:]·B_gh[n,:]  (bf16 out), K=1024 per block.
// Grid 256 = 8 z (id&7 -> one z per XCD) x 4 by x 8 bx; 512 threads = 8 waves (2M x 4N),
// per-wave output 128x64 via 8x4 of 16x16x32 bf16 MFMA.  BK=64, LDS 128 KiB:
// A/B each double-buffered as 2 halves of 128x64 (16 KiB stage units, 2 gload16/thread).
// Schedule (iteration i computes K-tiles T0=2i in phases 0-3, T1=2i+1 in 4-7; one stage
// unit issued per phase, counted s_waitcnt vmcnt(4) ONLY after ph3 and ph7 so loads stay
// in flight across barriers):
//   ph0: A(T1,h0)  ph1: A(T1,h1)  ph2: B(T0+2,h0)  ph3: B(T0+2,h1) +vmcnt(4)
//   ph4: A(T0+2,h0) ph5: A(T0+2,h1) ph6: B(T1+2,h0) ph7: B(T1+2,h1) +vmcnt(4)
// Every WAR is >=1 barrier after the slot's last read; every RAW is covered by the waits
// (oldest-8-of-12 loads landed = exactly the units the next tile needs).  Last iteration
// clamps the (out-of-range) stages and drains with vmcnt(0) at ph3.
// LDS XOR swizzle identical to the verified 128² kernel (pre-swizzled global source,
// matching XOR on ds_read: conflicts measured 0).

#define BARRIER() asm volatile("s_barrier" ::: "memory")

__device__ __forceinline__ void stage_half(const __hip_bfloat16* __restrict__ gp,
                                           short* lb, int t) {
    // 128 rows x 64 cols bf16 (16 KiB) = 1024 chunks of 16B; thread t does chunks t, t+512.
    // LDS dest is linear (wave-uniform base + lane*16); swizzle applied on the GLOBAL side.
    const int r0 = t >> 3;
    const int c0 = (t & 7) ^ (r0 & 7);
    gload16(gp + (size_t)r0 * 1024 + c0 * 8, (char*)lb + t * 16);
    const int r1 = r0 + 64;
    const int c1 = (t & 7) ^ (r1 & 7);
    gload16(gp + (size_t)r1 * 1024 + c1 * 8, (char*)lb + t * 16 + 8192);
}

// LDS map in shorts: A p0 @0, A p1 @16384, B p0 @32768, B p1 @49152; half offset 8192.
template<int P>
__device__ __forceinline__ void read_bf(const short8* L8, int wn_i, int lrow, int quad,
                                        short8 (&bfr)[4][2]) {
    const int bb8 = 4096 + P * 2048 + (wn_i >> 1) * 1024;   // short8 units
#pragma unroll
    for (int nt = 0; nt < 4; ++nt) {
        const int rb = (wn_i & 1) * 64 + nt * 16 + lrow;
#pragma unroll
        for (int ks = 0; ks < 2; ++ks)
            bfr[nt][ks] = L8[bb8 + (rb << 3) + ((ks * 4 + quad) ^ (rb & 7))];
    }
}

template<int P, int Q>
__device__ __forceinline__ void read_af(const short8* L8, int wm_i, int lrow, int quad,
                                        short8 (&af)[2][2]) {
    const int ab8 = P * 2048 + wm_i * 1024;
#pragma unroll
    for (int sub = 0; sub < 2; ++sub) {
        const int ra = Q * 32 + sub * 16 + lrow;
#pragma unroll
        for (int ks = 0; ks < 2; ++ks)
            af[sub][ks] = L8[ab8 + (ra << 3) + ((ks * 4 + quad) ^ (ra & 7))];
    }
}

template<int Q>
__device__ __forceinline__ void mfma_q(short8 (&af)[2][2], short8 (&bfr)[4][2],
                                       float4v (&acc)[8][4]) {
    __builtin_amdgcn_s_setprio(1);
#pragma unroll
    for (int sub = 0; sub < 2; ++sub)
#pragma unroll
        for (int nt = 0; nt < 4; ++nt)
#pragma unroll
            for (int ks = 0; ks < 2; ++ks)
                acc[2 * Q + sub][nt] = __builtin_amdgcn_mfma_f32_16x16x32_bf16(
                    af[sub][ks], bfr[nt][ks], acc[2 * Q + sub][nt], 0, 0, 0);
    __builtin_amdgcn_s_setprio(0);
}

__global__ __launch_bounds__(512, 2) void gemm_split(
    const __hip_bfloat16* __restrict__ ws18,  // 18 x 1M bf16 per prep_all map
    __hip_bfloat16* __restrict__ part) {      // 8 x BH bf16
    const int id = blockIdx.x;
    const int z = id & 7;
    const int w = id >> 3;
    const int by = w & 3;
    const int bx = w >> 2;
    const int g = z >> 1, half = z & 1;
    const __hip_bfloat16* Ap = half ? (ws18 + (size_t)(10 + 2 * g) * WSEG)
                                    : (ws18 + (size_t)8 * WSEG);
    const __hip_bfloat16* Bp = half ? (ws18 + (size_t)(4 + g) * WSEG)
                                    : (ws18 + (size_t)g * WSEG);

    __shared__ short lds[65536];   // 128 KiB

    const int t = threadIdx.x;
    const int m0 = bx * 256, n0 = by * 256;
    const int wid = t >> 6, lane = t & 63;
    const int wm_i = wid >> 2, wn_i = wid & 3;   // 2 x 4 wave grid
    const int lrow = lane & 15, quad = lane >> 4;
    const short8* L8 = (const short8*)lds;

    float4v acc[8][4];
#pragma unroll
    for (int i = 0; i < 8; ++i)
#pragma unroll
        for (int j = 0; j < 4; ++j) acc[i][j] = (float4v){0.f, 0.f, 0.f, 0.f};

    auto stageA = [&](int k, int h) {
        stage_half(Ap + (size_t)(m0 + h * 128) * 1024 + (size_t)k * 64,
                   lds + (k & 1) * 16384 + h * 8192, t);
    };
    auto stageB = [&](int k, int h) {
        stage_half(Bp + (size_t)(n0 + h * 128) * 1024 + (size_t)k * 64,
                   lds + 32768 + (k & 1) * 16384 + h * 8192, t);
    };

    // prologue: tile0 fully + tile1's B halves (tile1's A streams in during ph0/ph1)
    stageA(0, 0); stageA(0, 1); stageB(0, 0); stageB(0, 1); stageB(1, 0); stageB(1, 1);
    asm volatile("s_waitcnt vmcnt(4)" ::: "memory");   // tile0's 4 units landed; B(1) in flight
    BARRIER();

    auto iter_body = [&](int i, bool last) {
        const int T1 = 2 * i + 1;
        short8 bfr[4][2];
        short8 af[2][2];

        // ---- phase 0 : T0, quadrant 0 (B-frags for whole tile read here) ----
        read_bf<0>(L8, wn_i, lrow, quad, bfr);
        read_af<0, 0>(L8, wm_i, lrow, quad, af);
        stageA(T1, 0);
        BARRIER(); __builtin_amdgcn_sched_barrier(0);
        mfma_q<0>(af, bfr, acc);
        BARRIER();

        // ---- phase 1 ----
        read_af<0, 1>(L8, wm_i, lrow, quad, af);
        stageA(T1, 1);
        BARRIER(); __builtin_amdgcn_sched_barrier(0);
        mfma_q<1>(af, bfr, acc);
        BARRIER();

        // ---- phase 2 ----
        read_af<0, 2>(L8, wm_i, lrow, quad, af);
        if (!last) stageB(T1 + 1, 0);
        BARRIER(); __builtin_amdgcn_sched_barrier(0);
        mfma_q<2>(af, bfr, acc);
        BARRIER();

        // ---- phase 3 : counted wait -> T1's A (ph0/1) + B (prev ph6/7) landed ----
        read_af<0, 3>(L8, wm_i, lrow, quad, af);
        if (!last) stageB(T1 + 1, 1);
        BARRIER(); __builtin_amdgcn_sched_barrier(0);
        mfma_q<3>(af, bfr, acc);
        if (last) asm volatile("s_waitcnt vmcnt(0)" ::: "memory");
        else      asm volatile("s_waitcnt vmcnt(4)" ::: "memory");
        BARRIER();

        // ---- phase 4 : T1, quadrant 0 ----
        read_bf<1>(L8, wn_i, lrow, quad, bfr);
        read_af<1, 0>(L8, wm_i, lrow, quad, af);
        if (!last) stageA(T1 + 1, 0);
        BARRIER(); __builtin_amdgcn_sched_barrier(0);
        mfma_q<0>(af, bfr, acc);
        BARRIER();

        // ---- phase 5 ----
        read_af<1, 1>(L8, wm_i, lrow, quad, af);
        if (!last) stageA(T1 + 1, 1);
        BARRIER(); __builtin_amdgcn_sched_barrier(0);
        mfma_q<1>(af, bfr, acc);
        BARRIER();

        // ---- phase 6 ----
        read_af<1, 2>(L8, wm_i, lrow, quad, af);
        if (!last) stageB(T1 + 2, 0);
        BARRIER(); __builtin_amdgcn_sched_barrier(0);
        mfma_q<2>(af, bfr, acc);
        BARRIER();

        // ---- phase 7 : counted wait -> next T0's B (ph2/3) + A (ph4/5) landed ----
        read_af<1, 3>(L8, wm_i, lrow, quad, af);
        if (!last) stageB(T1 + 2, 1);
        BARRIER(); __builtin_amdgcn_sched_barrier(0);
        mfma_q<3>(af, bfr, acc);
        if (!last) {
            asm volatile("s_waitcnt vmcnt(4)" ::: "memory");
            BARRIER();
        }
    };

#pragma unroll 1
    for (int i = 0; i < 7; ++i) iter_body(i, false);
    iter_body(7, true);

    // epilogue: C/D layout col=lane&15, row=quad*4+r (m89/m91 verified); bf16 partial
    __hip_bfloat16* pz = part + (size_t)z * BH;
#pragma unroll
    for (int mt = 0; mt < 8; ++mt) {
        const int rowb = m0 + wm_i * 128 + mt * 16 + quad * 4;
#pragma unroll
        for (int nt = 0; nt < 4; ++nt) {
            const int col = n0 + wn_i * 64 + nt * 16 + lrow;
#pragma unroll
            for (int r = 0; r < 4; ++r)
                pz[(size_t)(rowb + r) * HDIM + col] = __float2bfloat16(acc[mt][nt][r]);
        }
    }
}

// ---------------- combine: sum split-K partials + bias -> gates -> h1, c1 (fp32 out) ----------------
__global__ __launch_bounds__(256) void combine_k(
    const uint2* __restrict__ part,   // 8 x BH bf16, as uint2 = 4 elems
    const float* __restrict__ bi, const float* __restrict__ bff,
    const float* __restrict__ bc, const float* __restrict__ bo,
    const float* __restrict__ c0, const float* __restrict__ mC,
    float4* __restrict__ out) {
    const int i = blockIdx.x * 256 + threadIdx.x;   // 4-elem group index over BH/4
    const int h4 = (i * 4 & (HDIM - 1)) >> 2;       // float4 index into biases

    float gate[4][4];
#pragma unroll
    for (int g = 0; g < 4; ++g) {
        uint2 p0 = part[(size_t)(2 * g) * (BH / 4) + i];
        uint2 p1 = part[(size_t)(2 * g + 1) * (BH / 4) + i];
        float2 a0 = up2(p0.x), a1 = up2(p0.y);
        float2 b0 = up2(p1.x), b1 = up2(p1.y);
        gate[g][0] = a0.x + b0.x;
        gate[g][1] = a0.y + b0.y;
        gate[g][2] = a1.x + b1.x;
        gate[g][3] = a1.y + b1.y;
    }
    float4 vbi = ((const float4*)bi)[h4];
    float4 vbf = ((const float4*)bff)[h4];
    float4 vbc = ((const float4*)bc)[h4];
    float4 vbo = ((const float4*)bo)[h4];
    float4 vc0 = ((const float4*)c0)[i];
    float4 vmc = ((const float4*)mC)[i];
    const float* pbi = (const float*)&vbi;
    const float* pbf = (const float*)&vbf;
    const float* pbc = (const float*)&vbc;
    const float* pbo = (const float*)&vbo;
    const float* pc0 = (const float*)&vc0;
    const float* pmc = (const float*)&vmc;

    float h1[4], c1[4];
#pragma unroll
    for (int j = 0; j < 4; ++j) {
        float xi = gate[0][j] + pbi[j];
        float xf = gate[1][j] + pbf[j];
        float xc = gate[2][j] + pbc[j];
        float xo = gate[3][j] + pbo[j];
        float I = 1.f / (1.f + __expf(-xi));
        float F = 1.f / (1.f + __expf(-xf));
        float C = tanhf(xc) * pmc[j];
        float O = 1.f / (1.f + __expf(-xo));
        c1[j] = F * pc0[j] + I * C;
        h1[j] = O * tanhf(c1[j]);
    }
    out[i] = make_float4(h1[0], h1[1], h1[2], h1[3]);
    out[BH / 4 + i] = make_float4(c1[0], c1[1], c1[2], c1[3]);
}

extern "C" void kernel_launch(void* const* d_in, const int* in_sizes, int n_in,
                              void* d_out, int out_size, void* d_ws, size_t ws_size,
                              hipStream_t stream) {
    const float* x   = (const float*)d_in[0];
    const float* h0  = (const float*)d_in[1];
    const float* c0  = (const float*)d_in[2];
    const float* wxi = (const float*)d_in[3];
    const float* wxf = (const float*)d_in[4];
    const float* wxc = (const float*)d_in[5];
    const float* wxo = (const float*)d_in[6];
    const float* whi = (const float*)d_in[7];
    const float* whf = (const float*)d_in[8];
    const float* whc = (const float*)d_in[9];
    const float* who = (const float*)d_in[10];
    const float* bi  = (const float*)d_in[11];
    const float* bf  = (const float*)d_in[12];
    const float* bc  = (const float*)d_in[13];
    const float* bo  = (const float*)d_in[14];
    const float* mI  = (const float*)d_in[15];
    const float* mF  = (const float*)d_in[16];
    const float* mC  = (const float*)d_in[17];
    const float* mO  = (const float*)d_in[18];
    const float* mCell = (const float*)d_in[19];

    // ws layout: 18*1M bf16 = 36 MB | part: 8*BH bf16 = 32 MB
    __hip_bfloat16* ws18 = (__hip_bfloat16*)d_ws;
    __hip_bfloat16* part = ws18 + (size_t)18 * WSEG;

    prep_all_k<<<dim3(WSEG / 4 / 256, 18), dim3(256), 0, stream>>>(
        wxi, wxf, wxc, wxo, whi, whf, whc, who, x, h0, mI, mF, mC, mO,
        (uint2*)ws18);

    gemm_split<<<dim3(256), dim3(512), 0, stream>>>(ws18, part);

    combine_k<<<dim3(BH / 4 / 256), dim3(256), 0, stream>>>(
        (const uint2*)part, bi, bf, bc, bo, c0, mCell, (float4*)d_out);
}